// Round 1
// baseline (1654.529 us; speedup 1.0000x reference)
//
#include <hip/hip_runtime.h>

#define EDIM 256
#define NROW 16384
#define NCODE 16384

// ---- async global->LDS, 4B per lane, dest = uniform base + lane*4
__device__ __forceinline__ void gll4(const float* g, float* l) {
  __builtin_amdgcn_global_load_lds((const __attribute__((address_space(1))) void*)g,
                                   (__attribute__((address_space(3))) void*)l, 4, 0, 0);
}

// ||e_j||^2 in double, rounded once to f32 (only matters at ~1e-13 -> any order fine)
__global__ __launch_bounds__(256) void k_es(const float* __restrict__ e,
                                            float* __restrict__ es) {
  const int row = blockIdx.x * 4 + (threadIdx.x >> 6);
  const int lane = threadIdx.x & 63;
  float4 v = *(const float4*)&e[row * EDIM + lane * 4];
  double s = (double)v.x * v.x + (double)v.y * v.y + (double)v.z * v.z + (double)v.w * v.w;
#pragma unroll
  for (int off = 32; off > 0; off >>= 1) s += __shfl_down(s, off, 64);
  if (lane == 0) es[row] = (float)s;
}

// Main: block = 64 rows x (16384/SPLIT) codes. A [k][m] via global_load_lds (natural
// layout: z is c-major over the 64 hw-contiguous rows). B [k][n] reg-transposed,
// prefetched one step ahead. Double-buffered, 80KB LDS -> 2 blocks/CU.
template <int SPLIT>
__global__ __launch_bounds__(256, 2) void k_main(const float* __restrict__ z,
                                                 const float* __restrict__ e,
                                                 const float* __restrict__ es,
                                                 float* __restrict__ candv,
                                                 int* __restrict__ candi,
                                                 int* __restrict__ outd) {
  extern __shared__ char smem[];
  float* As = (float*)smem;                              // [2][32][64]  16KB
  float* Bs = (float*)(smem + 16384);                    // [2][32][256] 64KB
  double* zred = (double*)(smem + 16384 + 32768);        // overlays Bs buf1 (dead by loop)
  float* zsf = (float*)(smem + 16384 + 32768 + 2048);    // overlays Bs buf1 (dead by loop)

  const int tid = threadIdx.x;
  const int lane = tid & 63;
  const int wv = tid >> 6;
  const int tm = tid & 7;        // row-group 0..7 (8 rows each)
  const int tn = tid >> 3;       // code-group 0..31 (8 codes each)

  const int rt = (int)blockIdx.x / SPLIT;
  const int sp = (int)blockIdx.x % SPLIT;
  const int bb = rt >> 4;
  const int hw0 = (rt & 15) << 6;
  const float* zb = z + bb * (EDIM * 1024) + hw0;  // + c*1024 + m

  const int codeBase = sp * (NCODE / SPLIT);
  const int NTILE = (NCODE / SPLIT) / 256;
  const int NSTEP = NTILE * 8;  // 8 K-chunks of 32 per 256-code tile

  // ---- stage A chunk (32 k-rows x 64 m) async; wave wv covers k rows wv*8..wv*8+7
  auto stageA = [&](int buf, int gts) {
    const int k0 = (gts & 7) * 32;
    const float* g0 = zb + (size_t)k0 * 1024 + lane;
    float* l0 = As + buf * 2048 + (wv * 8) * 64;
#pragma unroll
    for (int s = 0; s < 8; ++s) gll4(g0 + (size_t)(wv * 8 + s) * 1024, l0 + s * 64);
  };

  // ---- B prefetch: thread tid owns code row (ct*256+tid), reads its 32-k slice
  float4 bpre[8];
  auto loadB = [&](int gts) {
    const int ct = gts >> 3, k0 = (gts & 7) * 32;
    const float* g = e + (size_t)(codeBase + ct * 256 + tid) * 256 + k0;
#pragma unroll
    for (int s = 0; s < 8; ++s) bpre[s] = *(const float4*)(g + s * 4);
  };
  auto writeB = [&](int buf) {  // transpose to [k][n]; banks = tid%32 -> 2-way (free)
    float* bw_ = Bs + buf * 8192 + tid;
#pragma unroll
    for (int s = 0; s < 8; ++s) {
      bw_[(4 * s + 0) * 256] = bpre[s].x;
      bw_[(4 * s + 1) * 256] = bpre[s].y;
      bw_[(4 * s + 2) * 256] = bpre[s].z;
      bw_[(4 * s + 3) * 256] = bpre[s].w;
    }
  };

  // ---- prologue: issue step-0 staging, hide latency under ||z||^2 pass
  stageA(0, 0);
  loadB(0);
  {
    const int m = tid & 63, qt = tid >> 6;
    const float* zp = zb + (size_t)(qt * 64) * 1024 + m;
    double s = 0.0;
    for (int k = 0; k < 64; ++k) {
      float v = zp[(size_t)k * 1024];
      s = fma((double)v, (double)v, s);
    }
    zred[qt * 64 + m] = s;
  }
  writeB(0);
  __syncthreads();  // drains gll + ds writes; zred visible
  if (tid < 64) {
    double sz = (zred[tid] + zred[64 + tid]) + (zred[128 + tid] + zred[192 + tid]);
    zsf[tid] = (float)sz;  // single rounding to f32 (grid-shift-invariant vs ref)
  }
  __syncthreads();
  float zsr[8];
#pragma unroll
  for (int i = 0; i < 8; ++i) zsr[i] = zsf[tm * 8 + i];
  __syncthreads();  // zsf overlays Bs buf1: protect before buf1 is staged

  float bestv[8];
  int besti[8];
#pragma unroll
  for (int i = 0; i < 8; ++i) {
    bestv[i] = 3.402823466e+38f;
    besti[i] = 0;
  }

  float acc[8][8];
  int cur = 0;
#pragma unroll 1
  for (int step = 0; step < NSTEP; ++step) {
    const int kc = step & 7, ct = step >> 3;
    if (step + 1 < NSTEP) {
      stageA(cur ^ 1, step + 1);  // async
      loadB(step + 1);            // gathers land during compute
    }
    if (kc == 0) {
#pragma unroll
      for (int i = 0; i < 8; ++i)
#pragma unroll
        for (int j = 0; j < 8; ++j) acc[i][j] = 0.0f;
    }
    const float* ak = As + cur * 2048 + tm * 8;
    const float* bk = Bs + cur * 8192 + tn * 8;
#pragma unroll 4
    for (int k = 0; k < 32; ++k) {  // sequential k order: deterministic fp32 chain
      float4 a0 = *(const float4*)(ak + k * 64);
      float4 a1 = *(const float4*)(ak + k * 64 + 4);
      float4 b0 = *(const float4*)(bk + k * 256);
      float4 b1 = *(const float4*)(bk + k * 256 + 4);
      float av[8] = {a0.x, a0.y, a0.z, a0.w, a1.x, a1.y, a1.z, a1.w};
      float bw[8] = {b0.x, b0.y, b0.z, b0.w, b1.x, b1.y, b1.z, b1.w};
#pragma unroll
      for (int i = 0; i < 8; ++i)
#pragma unroll
        for (int j = 0; j < 8; ++j) acc[i][j] = fmaf(av[i], bw[j], acc[i][j]);
    }
    if (step + 1 < NSTEP) writeB(cur ^ 1);
    if (kc == 7) {
      // faithful fp32 reference semantics: d = fl(fl(zs+es) - 2*g); 2*g exact
      const int cb = codeBase + ct * 256 + tn * 8;
#pragma unroll
      for (int j = 0; j < 8; ++j) {
        float ej = es[cb + j];
#pragma unroll
        for (int i = 0; i < 8; ++i) {
          float d = (zsr[i] + ej) - 2.0f * acc[i][j];
          if (d < bestv[i]) {  // strict <: first (lowest) index wins ties
            bestv[i] = d;
            besti[i] = cb + j;
          }
        }
      }
    }
    __syncthreads();
    cur ^= 1;
  }

  // ---- block reduction across the 32 code-groups (index-aware tie-break)
  float* Lv = (float*)(smem + 16384);          // overlays Bs (compute done)
  int* Li = (int*)(smem + 16384 + 8192);
#pragma unroll
  for (int i = 0; i < 8; ++i) {
    Lv[(tm * 8 + i) * 32 + tn] = bestv[i];
    Li[(tm * 8 + i) * 32 + tn] = besti[i];
  }
  __syncthreads();
  if (tid < 64) {
    float bv = Lv[tid * 32];
    int bi = Li[tid * 32];
#pragma unroll 1
    for (int g2 = 1; g2 < 32; ++g2) {
      float v = Lv[tid * 32 + g2];
      int ii = Li[tid * 32 + g2];
      if (v < bv || (v == bv && ii < bi)) {
        bv = v;
        bi = ii;
      }
    }
    if (SPLIT == 1) {
      outd[rt * 64 + tid] = bi;
    } else {
      candv[sp * NROW + rt * 64 + tid] = bv;
      candi[sp * NROW + rt * 64 + tid] = bi;
    }
  }
}

__global__ __launch_bounds__(256) void k_merge(const float* __restrict__ candv,
                                               const int* __restrict__ candi,
                                               int* __restrict__ out) {
  int n = blockIdx.x * 256 + threadIdx.x;
  float v0 = candv[n], v1 = candv[NROW + n];
  int i0 = candi[n], i1 = candi[NROW + n];
  out[n] = (v1 < v0) ? i1 : i0;  // tie -> lower split -> lower index
}

extern "C" void kernel_launch(void* const* d_in, const int* in_sizes, int n_in,
                              void* d_out, int out_size, void* d_ws, size_t ws_size,
                              hipStream_t stream) {
  const float* z = (const float*)d_in[0];
  const float* e = (const float*)d_in[1];
  int* out = (int*)d_out;

  float* es = (float*)d_ws;                               // 64KB
  float* candv = (float*)((char*)d_ws + 65536);           // 128KB
  int* candi = (int*)((char*)d_ws + 65536 + 131072);      // 128KB

  k_es<<<dim3(NCODE / 4), dim3(256), 0, stream>>>(e, es);

  const size_t smem = 16384 + 65536;  // 80KB -> 2 blocks/CU
  if (ws_size >= 65536 + 131072 + 131072) {
    hipFuncSetAttribute(reinterpret_cast<const void*>(&k_main<2>),
                        hipFuncAttributeMaxDynamicSharedMemorySize, (int)smem);
    k_main<2><<<dim3(512), dim3(256), smem, stream>>>(z, e, es, candv, candi, out);
    k_merge<<<dim3(NROW / 256), dim3(256), 0, stream>>>(candv, candi, out);
  } else {
    hipFuncSetAttribute(reinterpret_cast<const void*>(&k_main<1>),
                        hipFuncAttributeMaxDynamicSharedMemorySize, (int)smem);
    k_main<1><<<dim3(256), dim3(256), smem, stream>>>(z, e, es, candv, candi, out);
  }
}